// Round 1
// baseline (555.750 us; speedup 1.0000x reference)
//
#include <hip/hip_runtime.h>

// ROI adaptive average pooling.
// B=8, C=1024, HW=14, N=512, FS=14, SCALE=1/16.
// out[n,c,i,j] = mean over fm[fm_no(n), c, x1+b0r(i):x1+b1r(i), y1+b0c(j):y1+b1c(j)]
// where b0 = (i*L)/14, b1 = ceil((i+1)*L/14), L = clipped ROI extent (1..14).
// Bin spans are at most 2x2 -> <=4 loads per output element.
// Output is 411 MB fp32 -> kernel is HBM-write-bound; use float4 stores.

#define C_       1024
#define FS_      14
#define PER_CH   (FS_ * FS_)        // 196
#define PER_IMG  (C_ * PER_CH)      // 200704

__global__ __launch_bounds__(256) void roi_pool_kernel(
    const float* __restrict__ tensor,
    const float* __restrict__ roi,
    float* __restrict__ out,
    int total4)
{
    int gid = blockIdx.x * blockDim.x + threadIdx.x;
    if (gid >= total4) return;

    int e   = gid * 4;                 // first of 4 consecutive output elems
    int n   = e / PER_IMG;             // ROI index
    int rnc = e - n * PER_IMG;
    int c   = rnc / PER_CH;            // channel
    int rem = rnc - c * PER_CH;        // 0..192, multiple of 4 -> same (n,c) for all 4

    // ROI row: [batch_idx, x1, y1, x2, y2] in 224-px coords. Broadcast-cached reads.
    const float* r = roi + n * 5;
    int fm = (int)r[0];
    float x1f = r[1] * 0.0625f;
    float y1f = r[2] * 0.0625f;
    float x2f = r[3] * 0.0625f;
    float y2f = r[4] * 0.0625f;
    int x1 = max((int)floorf(x1f), 0);
    int y1 = max((int)floorf(y1f), 0);
    int x2 = min((int)ceilf(x2f), FS_);
    int y2 = min((int)ceilf(y2f), FS_);
    int Lh = x2 - x1;                  // >= 1 guaranteed by input construction
    int Lw = y2 - y1;

    const float* fmp = tensor + (fm * C_ + c) * PER_CH;

    float v[4];
#pragma unroll
    for (int k = 0; k < 4; ++k) {
        int p = rem + k;
        int i = p / FS_;
        int j = p - i * FS_;
        // bin ranges (relative to x1/y1); sizes are 1 or 2
        int h0 = (i * Lh) / FS_;
        int h1 = ((i + 1) * Lh + FS_ - 1) / FS_;
        int w0 = (j * Lw) / FS_;
        int w1 = ((j + 1) * Lw + FS_ - 1) / FS_;
        float s = 0.0f;
        for (int h = h0; h < h1; ++h) {
            const float* row = fmp + (x1 + h) * FS_ + y1;
            for (int w = w0; w < w1; ++w)
                s += row[w];
        }
        v[k] = s / (float)((h1 - h0) * (w1 - w0));
    }

    float4 o;
    o.x = v[0]; o.y = v[1]; o.z = v[2]; o.w = v[3];
    *reinterpret_cast<float4*>(out + e) = o;
}

extern "C" void kernel_launch(void* const* d_in, const int* in_sizes, int n_in,
                              void* d_out, int out_size, void* d_ws, size_t ws_size,
                              hipStream_t stream) {
    const float* tensor = (const float*)d_in[0];   // [8,1024,14,14] f32
    const float* roi    = (const float*)d_in[1];   // [512,5] f32
    float* out = (float*)d_out;                    // [512,1024,14,14] f32

    int total4 = out_size / 4;                     // 25,690,112 float4 stores
    int threads = 256;
    int blocks = (total4 + threads - 1) / threads; // 100,352 blocks
    roi_pool_kernel<<<blocks, threads, 0, stream>>>(tensor, roi, out, total4);
}

// Round 2
// 532.110 us; speedup vs baseline: 1.0444x; 1.0444x over previous
//
#include <hip/hip_runtime.h>

// ROI adaptive average pooling — geometry-in-LDS version.
// B=8, C=1024, HW=14, N=512, FS=14, SCALE=1/16.
//
// Structure: PER_IMG = 200704 = 196*1024, so each 256-thread block (1024
// output elements = 256 float4 quads) belongs to exactly ONE ROI. Pooling
// geometry depends only on (roi, position p in 0..195):
//   bin spans are 1 or 2 -> each output = (v00 + mw*v01 + mh*v10 + mwh*v11)*inv
// with inv in {1, 0.5, 0.25} (exact powers of two -> selects, no fp division).
// Phase 1: 196 threads compute the geometry tables into LDS (SoA).
// Phase 2: each thread ds_read_b128's its 4 consecutive entries (rem%4==0 ->
// consecutive lanes tile LDS dwords perfectly, conflict-free), does 16 clamped
// dword gathers (L1-resident 6.4 MB input), 16 fma/mul, one float4 store.
// Kernel is then HBM-write-bound: 411 MB -> ~65 us floor.

#define C_       1024
#define FS_      14
#define PER_CH   196                 // 14*14
#define PER_IMG  (C_ * PER_CH)       // 200704
#define NBLK_PER_N (PER_IMG / 1024)  // 196 blocks per ROI

__global__ __launch_bounds__(256) void roi_pool_kernel(
    const float* __restrict__ tensor,
    const float* __restrict__ roi,
    float* __restrict__ out)
{
    // SoA geometry tables, 16B-aligned for ds_read_b128 (indexed by quad).
    __shared__ int4   s_a00[PER_CH / 4], s_a01[PER_CH / 4],
                      s_a10[PER_CH / 4], s_a11[PER_CH / 4];
    __shared__ float4 s_mw[PER_CH / 4], s_mh[PER_CH / 4],
                      s_mwh[PER_CH / 4], s_inv[PER_CH / 4];

    const unsigned bx = blockIdx.x;
    const unsigned n  = bx / NBLK_PER_N;   // ROI index (block-uniform)
    const unsigned bq = bx - n * NBLK_PER_N;

    // ROI row [batch_idx, x1, y1, x2, y2] in 224-px coords; uniform address
    // -> scalar loads.
    const float* r = roi + n * 5;
    const int fm = (int)r[0];
    const int x1 = max((int)floorf(r[1] * 0.0625f), 0);
    const int y1 = max((int)floorf(r[2] * 0.0625f), 0);
    const int x2 = min((int)ceilf(r[3] * 0.0625f), FS_);
    const int y2 = min((int)ceilf(r[4] * 0.0625f), FS_);
    const unsigned Lh = (unsigned)(x2 - x1);   // 1..14 guaranteed
    const unsigned Lw = (unsigned)(y2 - y1);

    const unsigned tid = threadIdx.x;
    if (tid < PER_CH) {
        const unsigned p = tid;
        const unsigned i = p / 14u;
        const unsigned j = p - i * 14u;
        const unsigned h0 = (i * Lh) / 14u;
        const unsigned h1 = ((i + 1u) * Lh + 13u) / 14u;
        const unsigned w0 = (j * Lw) / 14u;
        const unsigned w1 = ((j + 1u) * Lw + 13u) / 14u;
        const int dh = (int)(h1 - h0) - 1;     // 0 or 1
        const int dw = (int)(w1 - w0) - 1;     // 0 or 1
        const int a00 = (x1 + (int)h0) * FS_ + (y1 + (int)w0);
        ((int*)s_a00)[p] = a00;
        ((int*)s_a01)[p] = a00 + dw;               // aliases a00 when span==1
        ((int*)s_a10)[p] = a00 + FS_ * dh;
        ((int*)s_a11)[p] = a00 + FS_ * dh + dw;
        ((float*)s_mw)[p]  = (float)dw;
        ((float*)s_mh)[p]  = (float)dh;
        ((float*)s_mwh)[p] = (float)(dw & dh);
        const int cnt = (dh + 1) * (dw + 1);       // 1, 2, or 4
        ((float*)s_inv)[p] = (cnt == 1) ? 1.0f : ((cnt == 2) ? 0.5f : 0.25f);
    }
    __syncthreads();

    // This thread's quad: element offset within the ROI's [1024,196] output.
    const unsigned lofs = bq * 1024u + tid * 4u;
    const unsigned c    = lofs / 196u;
    const unsigned rem  = lofs - c * 196u;     // multiple of 4
    const unsigned q    = rem >> 2;

    const float* __restrict__ plane = tensor + ((unsigned)fm * C_ + c) * PER_CH;

    const int4   A00 = s_a00[q], A01 = s_a01[q], A10 = s_a10[q], A11 = s_a11[q];
    const float4 MW = s_mw[q], MH = s_mh[q], MWH = s_mwh[q], INV = s_inv[q];

    float4 o;
    {
        float v00 = plane[A00.x], v01 = plane[A01.x],
              v10 = plane[A10.x], v11 = plane[A11.x];
        o.x = (v00 + MW.x * v01 + MH.x * v10 + MWH.x * v11) * INV.x;
    }
    {
        float v00 = plane[A00.y], v01 = plane[A01.y],
              v10 = plane[A10.y], v11 = plane[A11.y];
        o.y = (v00 + MW.y * v01 + MH.y * v10 + MWH.y * v11) * INV.y;
    }
    {
        float v00 = plane[A00.z], v01 = plane[A01.z],
              v10 = plane[A10.z], v11 = plane[A11.z];
        o.z = (v00 + MW.z * v01 + MH.z * v10 + MWH.z * v11) * INV.z;
    }
    {
        float v00 = plane[A00.w], v01 = plane[A01.w],
              v10 = plane[A10.w], v11 = plane[A11.w];
        o.w = (v00 + MW.w * v01 + MH.w * v10 + MWH.w * v11) * INV.w;
    }

    *reinterpret_cast<float4*>(out + (size_t)bx * 1024u + tid * 4u) = o;
}

extern "C" void kernel_launch(void* const* d_in, const int* in_sizes, int n_in,
                              void* d_out, int out_size, void* d_ws, size_t ws_size,
                              hipStream_t stream) {
    const float* tensor = (const float*)d_in[0];   // [8,1024,14,14] f32
    const float* roi    = (const float*)d_in[1];   // [512,5] f32
    float* out = (float*)d_out;                    // [512,1024,14,14] f32

    const int blocks = out_size / 1024;            // 100,352 = 512 ROIs * 196
    roi_pool_kernel<<<blocks, 256, 0, stream>>>(tensor, roi, out);
}

// Round 3
// 408.418 us; speedup vs baseline: 1.3607x; 1.3029x over previous
//
#include <hip/hip_runtime.h>

// ROI adaptive average pooling — LDS-gather version.
// B=8, C=1024, HW=14, N=512, FS=14, SCALE=1/16.
//
// R2 post-mortem: kernel was L1-gather-bound (16 divergent global dword
// gathers per quad, ~13 cache lines touched per wave-inst). Fix: stage the
// input planes in LDS (coalesced float4 copies) and gather from LDS instead
// (ds_read_b32 ~5.8cyc/wave-inst vs ~13cyc L1).
//
// Block = 1 ROI x 32 channels: 32 planes (25,088 B) + geometry (6,272 B) in
// LDS -> 5 blocks/CU. Each thread owns a fixed quad-of-4 positions q (work
// mapping strides by 245 = 5*49 so q is iteration-invariant) and keeps its
// geometry (4x int4 byte-offsets, 4x float4 masks) in registers. Per
// iteration: 16 ds_read_b32 gathers + ~16 FMA + 1 coalesced float4 store.
// Floor: max(LDS-gather ~61us, HBM-write 411MB ~65us).

#define FS_      14
#define PER_CH   196               // 14*14
#define C_       1024
#define CPB      32                // channels per block
#define QPC      49                // float4-quads per channel (196/4)
#define NSTAGE4  (CPB * PER_CH / 4)  // 1568 float4 to stage
#define ACT      245               // active compute threads = 5*49

__global__ __launch_bounds__(256) void roi_pool_kernel(
    const float* __restrict__ tensor,
    const float* __restrict__ roi,
    float* __restrict__ out)
{
    __shared__ float s_plane[CPB * PER_CH];                       // 25,088 B
    __shared__ alignas(16) int   s_o00[PER_CH], s_o01[PER_CH],
                                 s_o10[PER_CH], s_o11[PER_CH];    // byte offsets
    __shared__ alignas(16) float s_mw[PER_CH], s_mh[PER_CH],
                                 s_mwh[PER_CH], s_inv[PER_CH];

    const unsigned bx = blockIdx.x;
    const unsigned n  = bx >> 5;            // ROI index
    const unsigned c0 = (bx & 31u) * CPB;   // first channel of this block

    // ROI row [batch_idx, x1, y1, x2, y2] in 224-px coords (uniform -> scalar).
    const float* r = roi + n * 5;
    const int fm = (int)r[0];
    const int x1 = max((int)floorf(r[1] * 0.0625f), 0);
    const int y1 = max((int)floorf(r[2] * 0.0625f), 0);
    const int x2 = min((int)ceilf(r[3] * 0.0625f), FS_);
    const int y2 = min((int)ceilf(r[4] * 0.0625f), FS_);
    const unsigned Lh = (unsigned)(x2 - x1);   // 1..14 guaranteed
    const unsigned Lw = (unsigned)(y2 - y1);

    const unsigned tid = threadIdx.x;

    // ---- Phase 1a: geometry tables (196 positions), byte offsets into a plane.
    if (tid < PER_CH) {
        const unsigned p = tid;
        const unsigned i = p / 14u;
        const unsigned j = p - i * 14u;
        const unsigned h0 = (i * Lh) / 14u;
        const unsigned h1 = ((i + 1u) * Lh + 13u) / 14u;
        const unsigned w0 = (j * Lw) / 14u;
        const unsigned w1 = ((j + 1u) * Lw + 13u) / 14u;
        const int dh = (int)(h1 - h0) - 1;     // 0 or 1
        const int dw = (int)(w1 - w0) - 1;     // 0 or 1
        const int a00 = (x1 + (int)h0) * FS_ + (y1 + (int)w0);
        s_o00[p] = a00 * 4;
        s_o01[p] = (a00 + dw) * 4;             // aliases a00 when span==1
        s_o10[p] = (a00 + FS_ * dh) * 4;
        s_o11[p] = (a00 + FS_ * dh + dw) * 4;
        s_mw[p]  = (float)dw;
        s_mh[p]  = (float)dh;
        s_mwh[p] = (float)(dw & dh);
        const int cnt = (dh + 1) * (dw + 1);   // 1, 2, or 4
        s_inv[p] = (cnt == 1) ? 1.0f : ((cnt == 2) ? 0.5f : 0.25f);
    }

    // ---- Phase 1b: stage the 32 contiguous input planes (coalesced float4).
    // Slice base is 784-byte aligned -> float4-safe.
    const float4* __restrict__ src4 =
        (const float4*)(tensor + ((size_t)fm * C_ + c0) * PER_CH);
    float4* __restrict__ dst4 = (float4*)s_plane;
#pragma unroll
    for (unsigned k = 0; k < 7; ++k) {
        unsigned fi = k * 256u + tid;
        if (fi < NSTAGE4) dst4[fi] = src4[fi];
    }

    __syncthreads();

    // ---- Phase 2: each active thread owns quad q of every 5th channel.
    if (tid < ACT) {
        const unsigned tc = tid / QPC;         // 0..4
        const unsigned q  = tid - tc * QPC;    // fixed across iterations

        const int4   O00 = ((const int4*)s_o00)[q];
        const int4   O01 = ((const int4*)s_o01)[q];
        const int4   O10 = ((const int4*)s_o10)[q];
        const int4   O11 = ((const int4*)s_o11)[q];
        const float4 MW  = ((const float4*)s_mw)[q];
        const float4 MH  = ((const float4*)s_mh)[q];
        const float4 MWH = ((const float4*)s_mwh)[q];
        const float4 INV = ((const float4*)s_inv)[q];

        float4* __restrict__ out4 =
            (float4*)(out + ((size_t)n * C_ + c0) * PER_CH);

#pragma unroll
        for (unsigned it = 0; it < 7; ++it) {
            const unsigned cl = it * 5u + tc;  // local channel
            if (cl >= CPB) continue;           // only trims the last iteration
            const char* pb = (const char*)s_plane + cl * (PER_CH * 4);

            float4 o;
            {
                float v00 = *(const float*)(pb + O00.x);
                float v01 = *(const float*)(pb + O01.x);
                float v10 = *(const float*)(pb + O10.x);
                float v11 = *(const float*)(pb + O11.x);
                o.x = (v00 + MW.x * v01 + MH.x * v10 + MWH.x * v11) * INV.x;
            }
            {
                float v00 = *(const float*)(pb + O00.y);
                float v01 = *(const float*)(pb + O01.y);
                float v10 = *(const float*)(pb + O10.y);
                float v11 = *(const float*)(pb + O11.y);
                o.y = (v00 + MW.y * v01 + MH.y * v10 + MWH.y * v11) * INV.y;
            }
            {
                float v00 = *(const float*)(pb + O00.z);
                float v01 = *(const float*)(pb + O01.z);
                float v10 = *(const float*)(pb + O10.z);
                float v11 = *(const float*)(pb + O11.z);
                o.z = (v00 + MW.z * v01 + MH.z * v10 + MWH.z * v11) * INV.z;
            }
            {
                float v00 = *(const float*)(pb + O00.w);
                float v01 = *(const float*)(pb + O01.w);
                float v10 = *(const float*)(pb + O10.w);
                float v11 = *(const float*)(pb + O11.w);
                o.w = (v00 + MW.w * v01 + MH.w * v10 + MWH.w * v11) * INV.w;
            }

            out4[it * ACT + tid] = o;          // qq = it*245+tid, coalesced
        }
    }
}

extern "C" void kernel_launch(void* const* d_in, const int* in_sizes, int n_in,
                              void* d_out, int out_size, void* d_ws, size_t ws_size,
                              hipStream_t stream) {
    const float* tensor = (const float*)d_in[0];   // [8,1024,14,14] f32
    const float* roi    = (const float*)d_in[1];   // [512,5] f32
    float* out = (float*)d_out;                    // [512,1024,14,14] f32

    const int blocks = (out_size / (CPB * PER_CH));  // 512 * 32 = 16,384
    roi_pool_kernel<<<blocks, 256, 0, stream>>>(tensor, roi, out);
}